// Round 12
// baseline (510.523 us; speedup 1.0000x reference)
//
#include <hip/hip_runtime.h>

// ---------------------------------------------------------------------------
// LowFreqSparseAttention: qkv 1x1conv -> l2norm(q,k) -> S=QK^T*scale ->
// top-k(k=N/2) mask -> softmax -> PV -> proj 1x1conv -> GroupNorm(32 groups).
// B=1, C=256, H=W=64 -> N=4096, 8 heads, hd=32, k_sel=2048.
//
// R25 = R19 structure + dot2-PV with ON-THE-FLY u8->fp16 decode.
// R24 post-mortem: dot2-PV cut issue (absmax halved, spill gone: WRITE
// 20MB->4MB) but the 32KB fp16 weight store cost occupancy 51.5->41.5%
// -> net -4%. Recombine: keep R19's u8 wtsT[4096][4] (16KB, proven
// 4 blocks/CU) and decode pairs in phase5:
//   per 2-m iter: 1 LDS b64 (adjacent pair words) + 2 coalesced float4 V
//   + 8 v_cvt_f32_ubyte + 8 cvt_pkrtz + 16 v_dot2_f32_f16  (~38 insts
//   vs 44 scalar) -- ~14% less phase-5 issue at IDENTICAL occupancy.
// Everything else (GEMM, l2norms, phases 1-4, R19 selection window
// it<8 && width>65536 cap 40) is R19 verbatim.
// Predict: LDS 19456, occ ~50%, attn ~380-400, total ~475-495,
// FETCH ~6MB WRITE ~4MB, absmax <= 0.0313.
// Falsif.: attn >= 410 at 50% occ -> R19-class structure at its floor.
// ---------------------------------------------------------------------------

#define NTOK 4096
#define HD 32
#define NHEADS 8
#define KSEL 2048
#define SCALE 0.17677669529663689f   // 32^-0.5  (folded into l2norm_q)
#define LOG2C 7.73937f               // log2(255 / e^0.1767767)

typedef __fp16 f16x2 __attribute__((ext_vector_type(2)));

// ---- helpers --------------------------------------------------------------

__device__ __forceinline__ unsigned fkey(float f) {
  unsigned b = __float_as_uint(f);
  return (b & 0x80000000u) ? ~b : (b | 0x80000000u);
}
__device__ __forceinline__ float unfkey(unsigned k) {
  unsigned b = (k & 0x80000000u) ? (k ^ 0x80000000u) : ~k;
  return __uint_as_float(b);
}
__device__ __forceinline__ unsigned rfl_u(unsigned x) {  // force SGPR
  return __builtin_amdgcn_readfirstlane(x);
}
// regula-falsi probe in key space, clamped to (klo, khi]
__device__ __forceinline__ unsigned probe_rf(unsigned klo, unsigned khi,
                                             float xlo, float xhi,
                                             int clo, int chi) {
  float t = xlo + (xhi - xlo) * ((float)(clo - KSEL) / (float)(clo - chi));
  unsigned k = fkey(t);
  if (k <= klo) k = klo + 1u;
  if (k > khi) k = khi;
  return k;
}

// ---- kernel 1/4: GEMM  C[M][4096] = A[M][256] * B[256][4096] --------------
// SCATTER: M=768 -> Q [h][n][d], KT [h][d][n] (transposed!), V [h][n][d].
// else:    M=256 -> plain row-major C0.

template <bool SCATTER>
__global__ __launch_bounds__(256) void gemm_k256(
    const float* __restrict__ A, const float* __restrict__ B,
    float* __restrict__ C0, float* __restrict__ C1, float* __restrict__ C2) {
  __shared__ float Wt[64][17];   // +1 pad: avoid 16-way bank conflict
  __shared__ float Xt[16][64];

  const int tid = threadIdx.x;
  const int tx = tid & 15, ty = tid >> 4;
  const int o0 = blockIdx.y * 64, n0 = blockIdx.x * 64;

  const int wr = tid >> 2, wc = (tid & 3) << 2;   // W-tile 64x16 loader
  const int xr = tid >> 4, xc = (tid & 15) << 2;  // X-tile 16x64 loader

  float4 acc[4];
#pragma unroll
  for (int i = 0; i < 4; ++i) acc[i] = make_float4(0.f, 0.f, 0.f, 0.f);

  for (int k0 = 0; k0 < 256; k0 += 16) {
    float4 wv = *(const float4*)(A + (o0 + wr) * 256 + k0 + wc);
    float4 xv = *(const float4*)(B + (k0 + xr) * 4096 + n0 + xc);
    Wt[wr][wc + 0] = wv.x; Wt[wr][wc + 1] = wv.y;
    Wt[wr][wc + 2] = wv.z; Wt[wr][wc + 3] = wv.w;
    *(float4*)&Xt[xr][xc] = xv;
    __syncthreads();
#pragma unroll
    for (int kk = 0; kk < 16; ++kk) {
      float4 b = *(const float4*)&Xt[kk][tx << 2];
#pragma unroll
      for (int i = 0; i < 4; ++i) {
        float a = Wt[(ty << 2) + i][kk];
        acc[i].x += a * b.x; acc[i].y += a * b.y;
        acc[i].z += a * b.z; acc[i].w += a * b.w;
      }
    }
    __syncthreads();
  }

  if (SCATTER) {
#pragma unroll
    for (int i = 0; i < 4; ++i) {
      int o = o0 + (ty << 2) + i;
      int which = o >> 8, rem = o & 255;
      int h = rem >> 5, d = rem & 31;
      int n = n0 + (tx << 2);
      if (which == 1) {
        // KT[h][d][n..n+3]: contiguous float4
        *(float4*)(C1 + h * (HD * NTOK) + d * NTOK + n) = acc[i];
      } else {
        float* dst = (which == 0) ? C0 : C2;
        int base = h * (NTOK * HD) + d;
        dst[base + (n + 0) * HD] = acc[i].x;
        dst[base + (n + 1) * HD] = acc[i].y;
        dst[base + (n + 2) * HD] = acc[i].z;
        dst[base + (n + 3) * HD] = acc[i].w;
      }
    }
  } else {
#pragma unroll
    for (int i = 0; i < 4; ++i) {
      int o = o0 + (ty << 2) + i;
      *(float4*)(C0 + o * 4096 + n0 + (tx << 2)) = acc[i];
    }
  }
}

// ---- kernel 2a: l2norm Q rows [h][n][32], folds SCALE ---------------------

__global__ __launch_bounds__(256) void l2norm_q(float* __restrict__ Q) {
  const int tid = threadIdx.x;
  const int p = blockIdx.x * 8 + (tid >> 5);  // (head*4096+n) row index
  const int d = tid & 31;
  const int idx = p * HD + d;
  float v = Q[idx];
  float ss = v * v;
#pragma unroll
  for (int m = 16; m >= 1; m >>= 1) ss += __shfl_xor(ss, m, 32);
  float nrm = sqrtf(ss);
  Q[idx] = v * SCALE / fmaxf(nrm, 1e-12f);
}

// ---- kernel 2b: l2norm KT columns (norm over d at fixed n) ----------------

__global__ __launch_bounds__(256) void l2norm_kt(float* __restrict__ KT) {
  const int n = blockIdx.x * 256 + threadIdx.x;
  float* P = KT + blockIdx.y * (HD * NTOK) + n;
  float v[HD];
  float ss = 0.f;
#pragma unroll
  for (int d = 0; d < HD; ++d) {
    v[d] = P[d * NTOK];          // coalesced across lanes
    ss += v[d] * v[d];
  }
  float inv = 1.f / fmaxf(sqrtf(ss), 1e-12f);
#pragma unroll
  for (int d = 0; d < HD; ++d) P[d * NTOK] = v[d] * inv;
}

// ---- kernel 3: fused attention (4 rows per block, column-partitioned) -----
// phase2: thread tid owns cols {g*1024 + tid*4 + t}; computes ALL 4 rows.
//         q via per-(dg,dd) ds_read_b32 broadcast; all 4 kv float4 issued
//         together per dd (MLP). Loops unroll-bounded (no LICM explosion).
// phase3: hybrid selection (R19 window: RF while it<8 && width>65536, then
//         ulp bisection). Counts readfirstlane'd -> state SALU/SGPR;
//         per-row done-guards skip converged ballots.
// phase4: u8 weights packed 4 rows/col -> ONE ds_write_b128 per 4 cols;
//         exact integer denominators, block-reduced.  (R19 verbatim)
// phase5: PV via v_dot2_f32_f16 over m-pairs with on-the-fly u8->fp16
//         decode (cvt_f32_ubyte + cvt_pkrtz); V fp32 loads coalesced.

__global__ __launch_bounds__(256, 5) void attn_kernel(
    const float* __restrict__ Q, const float* __restrict__ KT,
    const float* __restrict__ V, float* __restrict__ AO) {
  __shared__ __align__(16) unsigned char wtsT[NTOK][4];   // 16 KB, [m][row]
  __shared__ float qs[128];
  __shared__ float pvred[4 * 8 * 4 * 4];                  // 2 KB
  __shared__ unsigned ired[2][4][2];                      // bisection dbuf
  __shared__ unsigned dred[4][4];                         // denom partials

  const int tid = threadIdx.x;
  const int wv = tid >> 6, lane = tid & 63;
  const int head = blockIdx.x & 7;          // head == blockIdx%8 -> XCD-pinned
  const int n0 = (blockIdx.x >> 3) << 2;

  const float* Qh = Q + head * (NTOK * HD);
  const float* KTh = KT + head * (HD * NTOK);
  const float* Vh = V + head * (NTOK * HD);

  // phase 1: stage the block's 4 q rows (already *SCALE from l2norm_q)
  if (tid < 128) qs[tid] = Qh[n0 * HD + tid];
  __syncthreads();

  // phase 2: kr[r][g*4+t] = score(row r, col g*1024 + tid*4 + t).
  // Each K element is read by exactly ONE thread of the block. Per (dg,dd):
  // 4 scalar q broadcasts (ds_read_b32) + 4 kv float4 issued together.
  float kr[4][16];
#pragma unroll
  for (int r = 0; r < 4; ++r)
#pragma unroll
    for (int j = 0; j < 16; ++j) kr[r][j] = 0.f;

  const int cb = tid << 2;
  const float* kbase = KTh + cb;
#define QK8(r, q, a, b, j0)                                                  \
  kr[r][(j0) + 0] += (q) * (a).x; kr[r][(j0) + 1] += (q) * (a).y;            \
  kr[r][(j0) + 2] += (q) * (a).z; kr[r][(j0) + 3] += (q) * (a).w;            \
  kr[r][(j0) + 4] += (q) * (b).x; kr[r][(j0) + 5] += (q) * (b).y;            \
  kr[r][(j0) + 6] += (q) * (b).z; kr[r][(j0) + 7] += (q) * (b).w;
#pragma unroll 1
  for (int dg = 0; dg < 8; ++dg) {
#pragma unroll 1
    for (int dd = 0; dd < 4; ++dd) {
      const int d = (dg << 2) + dd;
      const float* kp = kbase + d * NTOK;
      // all 4 global loads issued before any use (MLP)
      const float4 a0 = *(const float4*)(kp);
      const float4 b0 = *(const float4*)(kp + 1024);
      const float4 a1 = *(const float4*)(kp + 2048);
      const float4 b1 = *(const float4*)(kp + 3072);
      const float q0 = qs[d];            // ds_read_b32 broadcast
      const float q1 = qs[HD + d];
      const float q2 = qs[2 * HD + d];
      const float q3 = qs[3 * HD + d];
      QK8(0, q0, a0, b0, 0) QK8(1, q1, a0, b0, 0)
      QK8(2, q2, a0, b0, 0) QK8(3, q3, a0, b0, 0)
      QK8(0, q0, a1, b1, 8) QK8(1, q1, a1, b1, 8)
      QK8(2, q2, a1, b1, 8) QK8(3, q3, a1, b1, 8)
    }
  }
#undef QK8

  // phase 3: hybrid selection per row (R19 schedule). Bracket invariant
  // (key space): count(klo) >= KSEL, answer in [klo, khi]. RF probe while
  // it<8 && width>65536; ulp midpoint after. Exit on count==KSEL (kept set
  // == reference's top-k; ties make the count skip KSEL so ==KSEL is
  // tie-free) or klo==khi (exact kth key).
  // |scores| <= 0.1768 < 0.25, so anchors (-0.25 -> 4096, +0.25 -> 0).
  // State block-uniform; counts readfirstlane'd -> SGPR/SALU resident.
  unsigned klo0 = 0x417FFFFFu, khi0 = 0xBE800000u;  // fkey(-.25), fkey(.25)
  unsigned klo1 = 0x417FFFFFu, khi1 = 0xBE800000u;
  unsigned klo2 = 0x417FFFFFu, khi2 = 0xBE800000u;
  unsigned klo3 = 0x417FFFFFu, khi3 = 0xBE800000u;
  float xlo0 = -0.25f, xhi0 = 0.25f, xlo1 = -0.25f, xhi1 = 0.25f;
  float xlo2 = -0.25f, xhi2 = 0.25f, xlo3 = -0.25f, xhi3 = 0.25f;
  int clo0 = NTOK, chi0 = 0, clo1 = NTOK, chi1 = 0;
  int clo2 = NTOK, chi2 = 0, clo3 = NTOK, chi3 = 0;
  bool dn0 = false, dn1 = false, dn2 = false, dn3 = false;
  int slot = 0;
#pragma unroll 1
  for (int it = 0; it < 40; ++it) {
    unsigned m0 = dn0 ? klo0
        : ((it < 8 && (khi0 - klo0) > 65536u)
               ? rfl_u(probe_rf(klo0, khi0, xlo0, xhi0, clo0, chi0))
               : klo0 + ((khi0 - klo0 + 1u) >> 1));
    unsigned m1 = dn1 ? klo1
        : ((it < 8 && (khi1 - klo1) > 65536u)
               ? rfl_u(probe_rf(klo1, khi1, xlo1, xhi1, clo1, chi1))
               : klo1 + ((khi1 - klo1 + 1u) >> 1));
    unsigned m2 = dn2 ? klo2
        : ((it < 8 && (khi2 - klo2) > 65536u)
               ? rfl_u(probe_rf(klo2, khi2, xlo2, xhi2, clo2, chi2))
               : klo2 + ((khi2 - klo2 + 1u) >> 1));
    unsigned m3 = dn3 ? klo3
        : ((it < 8 && (khi3 - klo3) > 65536u)
               ? rfl_u(probe_rf(klo3, khi3, xlo3, xhi3, clo3, chi3))
               : klo3 + ((khi3 - klo3 + 1u) >> 1));
    unsigned c0 = 0, c1 = 0, c2 = 0, c3 = 0;
    if (!dn0) {
      const float f0 = unfkey(m0);
#pragma unroll
      for (int j = 0; j < 16; ++j) c0 += __popcll(__ballot(kr[0][j] >= f0));
    }
    if (!dn1) {
      const float f1 = unfkey(m1);
#pragma unroll
      for (int j = 0; j < 16; ++j) c1 += __popcll(__ballot(kr[1][j] >= f1));
    }
    if (!dn2) {
      const float f2 = unfkey(m2);
#pragma unroll
      for (int j = 0; j < 16; ++j) c2 += __popcll(__ballot(kr[2][j] >= f2));
    }
    if (!dn3) {
      const float f3 = unfkey(m3);
#pragma unroll
      for (int j = 0; j < 16; ++j) c3 += __popcll(__ballot(kr[3][j] >= f3));
    }
    if (lane == 0) {
      ired[slot][wv][0] = c0 | (c1 << 16);
      ired[slot][wv][1] = c2 | (c3 << 16);
    }
    __syncthreads();
    unsigned a01 = rfl_u(ired[slot][0][0] + ired[slot][1][0] +
                         ired[slot][2][0] + ired[slot][3][0]);
    unsigned a23 = rfl_u(ired[slot][0][1] + ired[slot][1][1] +
                         ired[slot][2][1] + ired[slot][3][1]);
    slot ^= 1;
    int C0 = (int)(a01 & 0xFFFFu), C1 = (int)(a01 >> 16);
    int C2 = (int)(a23 & 0xFFFFu), C3 = (int)(a23 >> 16);
#define BUPD(C, klo, khi, xlo, xhi, clo, chi, dn, mk)                        \
    if (!dn) {                                                               \
      if (C == KSEL) { klo = mk; dn = true; }                                \
      else if (C > KSEL) { klo = mk; xlo = unfkey(mk); clo = C; }            \
      else { khi = mk - 1u; xhi = unfkey(mk); chi = C; }                     \
      if (klo >= khi) dn = true;                                             \
    }
    BUPD(C0, klo0, khi0, xlo0, xhi0, clo0, chi0, dn0, m0)
    BUPD(C1, klo1, khi1, xlo1, xhi1, clo1, chi1, dn1, m1)
    BUPD(C2, klo2, khi2, xlo2, xhi2, clo2, chi2, dn2, m2)
    BUPD(C3, klo3, khi3, xlo3, xhi3, clo3, chi3, dn3, m3)
#undef BUPD
    if (dn0 && dn1 && dn2 && dn3) break;   // uniform across block
  }
  const float tf0 = unfkey(klo0), tf1 = unfkey(klo1);
  const float tf2 = unfkey(klo2), tf3 = unfkey(klo3);

  // phase 4: u8 weights, 4 rows packed per column, b128 per 4 columns.
  // u = rint(exp(s) * 255/e^smax) in [179,255] kept, 0 masked. (R19)
  unsigned id0 = 0, id1 = 0, id2 = 0, id3 = 0;
#pragma unroll
  for (int g = 0; g < 4; ++g) {
    unsigned pk[4];
#pragma unroll
    for (int t = 0; t < 4; ++t) {
      const int j = (g << 2) + t;
      float s0 = kr[0][j], s1 = kr[1][j], s2 = kr[2][j], s3 = kr[3][j];
      unsigned u0 = (s0 >= tf0) ? (unsigned)rintf(exp2f(__builtin_fmaf(s0, 1.44269504f, LOG2C))) : 0u;
      unsigned u1 = (s1 >= tf1) ? (unsigned)rintf(exp2f(__builtin_fmaf(s1, 1.44269504f, LOG2C))) : 0u;
      unsigned u2 = (s2 >= tf2) ? (unsigned)rintf(exp2f(__builtin_fmaf(s2, 1.44269504f, LOG2C))) : 0u;
      unsigned u3 = (s3 >= tf3) ? (unsigned)rintf(exp2f(__builtin_fmaf(s3, 1.44269504f, LOG2C))) : 0u;
      id0 += u0; id1 += u1; id2 += u2; id3 += u3;
      pk[t] = u0 | (u1 << 8) | (u2 << 16) | (u3 << 24);
    }
    const int col = (g << 10) + cb;            // addr = col*4, 16B-aligned
    *(uint4*)&wtsT[col][0] = make_uint4(pk[0], pk[1], pk[2], pk[3]);
  }
  // exact integer denominators: wave-reduce then cross-wave sum
#pragma unroll
  for (int s = 1; s < 64; s <<= 1) {
    id0 += __shfl_xor(id0, s); id1 += __shfl_xor(id1, s);
    id2 += __shfl_xor(id2, s); id3 += __shfl_xor(id3, s);
  }
  if (lane == 0) *(uint4*)&dred[wv][0] = make_uint4(id0, id1, id2, id3);
  __syncthreads();  // wtsT + dred visible to all
  const float dnm0 = (float)(dred[0][0] + dred[1][0] + dred[2][0] + dred[3][0]);
  const float dnm1 = (float)(dred[0][1] + dred[1][1] + dred[2][1] + dred[3][1]);
  const float dnm2 = (float)(dred[0][2] + dred[1][2] + dred[2][2] + dred[3][2]);
  const float dnm3 = (float)(dred[0][3] + dred[1][3] + dred[2][3] + dred[3][3]);

  // phase 5: PV via dot2 over m-pairs with on-the-fly u8->fp16 decode.
  // Wave wv covers m in [wv*1024,+1024): iter ii, lane-group mg handles
  // pair (mp, mp+1), mp = mbase + 16*ii + 2*mg. LDS: ONE b64 read gives
  // both m-words (broadcast over 8 lanes, consecutive banks over mg ->
  // conflict-free). V: two coalesced float4 rows (R11 pattern).
  const int slot5 = lane & 7, mg = lane >> 3;
  const int mbase = wv << 10;
  float av[4][4];
#pragma unroll
  for (int r = 0; r < 4; ++r)
#pragma unroll
    for (int c = 0; c < 4; ++c) av[r][c] = 0.f;

#pragma unroll 4
  for (int ii = 0; ii < 64; ++ii) {
    const int mp = mbase + (ii << 4) + (mg << 1);
    const uint2 wq = *(const uint2*)&wtsT[mp][0];  // x: rows@m, y: rows@m+1
    const float4 va = *(const float4*)(Vh + mp * HD + (slot5 << 2));
    const float4 vb = *(const float4*)(Vh + (mp + 1) * HD + (slot5 << 2));
    const float w0a = (float)(wq.x & 0xFFu),        w0b = (float)(wq.y & 0xFFu);
    const float w1a = (float)((wq.x >> 8) & 0xFFu), w1b = (float)((wq.y >> 8) & 0xFFu);
    const float w2a = (float)((wq.x >> 16) & 0xFFu),w2b = (float)((wq.y >> 16) & 0xFFu);
    const float w3a = (float)(wq.x >> 24),          w3b = (float)(wq.y >> 24);
#if __has_builtin(__builtin_amdgcn_fdot2) && __has_builtin(__builtin_amdgcn_cvt_pkrtz)
    const f16x2 vp0 = __builtin_amdgcn_cvt_pkrtz(va.x, vb.x);
    const f16x2 vp1 = __builtin_amdgcn_cvt_pkrtz(va.y, vb.y);
    const f16x2 vp2 = __builtin_amdgcn_cvt_pkrtz(va.z, vb.z);
    const f16x2 vp3 = __builtin_amdgcn_cvt_pkrtz(va.w, vb.w);
    const f16x2 w0 = __builtin_amdgcn_cvt_pkrtz(w0a, w0b);  // ints <=255 exact
    const f16x2 w1 = __builtin_amdgcn_cvt_pkrtz(w1a, w1b);
    const f16x2 w2 = __builtin_amdgcn_cvt_pkrtz(w2a, w2b);
    const f16x2 w3 = __builtin_amdgcn_cvt_pkrtz(w3a, w3b);
    av[0][0] = __builtin_amdgcn_fdot2(w0, vp0, av[0][0], false);
    av[0][1] = __builtin_amdgcn_fdot2(w0, vp1, av[0][1], false);
    av[0][2] = __builtin_amdgcn_fdot2(w0, vp2, av[0][2], false);
    av[0][3] = __builtin_amdgcn_fdot2(w0, vp3, av[0][3], false);
    av[1][0] = __builtin_amdgcn_fdot2(w1, vp0, av[1][0], false);
    av[1][1] = __builtin_amdgcn_fdot2(w1, vp1, av[1][1], false);
    av[1][2] = __builtin_amdgcn_fdot2(w1, vp2, av[1][2], false);
    av[1][3] = __builtin_amdgcn_fdot2(w1, vp3, av[1][3], false);
    av[2][0] = __builtin_amdgcn_fdot2(w2, vp0, av[2][0], false);
    av[2][1] = __builtin_amdgcn_fdot2(w2, vp1, av[2][1], false);
    av[2][2] = __builtin_amdgcn_fdot2(w2, vp2, av[2][2], false);
    av[2][3] = __builtin_amdgcn_fdot2(w2, vp3, av[2][3], false);
    av[3][0] = __builtin_amdgcn_fdot2(w3, vp0, av[3][0], false);
    av[3][1] = __builtin_amdgcn_fdot2(w3, vp1, av[3][1], false);
    av[3][2] = __builtin_amdgcn_fdot2(w3, vp2, av[3][2], false);
    av[3][3] = __builtin_amdgcn_fdot2(w3, vp3, av[3][3], false);
#else
    av[0][0] += w0a * va.x + w0b * vb.x; av[0][1] += w0a * va.y + w0b * vb.y;
    av[0][2] += w0a * va.z + w0b * vb.z; av[0][3] += w0a * va.w + w0b * vb.w;
    av[1][0] += w1a * va.x + w1b * vb.x; av[1][1] += w1a * va.y + w1b * vb.y;
    av[1][2] += w1a * va.z + w1b * vb.z; av[1][3] += w1a * va.w + w1b * vb.w;
    av[2][0] += w2a * va.x + w2b * vb.x; av[2][1] += w2a * va.y + w2b * vb.y;
    av[2][2] += w2a * va.z + w2b * vb.z; av[2][3] += w2a * va.w + w2b * vb.w;
    av[3][0] += w3a * va.x + w3b * vb.x; av[3][1] += w3a * va.y + w3b * vb.y;
    av[3][2] += w3a * va.z + w3b * vb.z; av[3][3] += w3a * va.w + w3b * vb.w;
#endif
  }
  // reduce over mg (lane bits 3..5)
#pragma unroll
  for (int r = 0; r < 4; ++r)
#pragma unroll
    for (int c = 0; c < 4; ++c) {
      float x = av[r][c];
      x += __shfl_xor(x, 8); x += __shfl_xor(x, 16); x += __shfl_xor(x, 32);
      av[r][c] = x;
    }
  if (mg == 0) {
#pragma unroll
    for (int r = 0; r < 4; ++r)
#pragma unroll
      for (int c = 0; c < 4; ++c)
        pvred[(((wv << 3) + slot5) * 4 + r) * 4 + c] = av[r][c];
  }
  __syncthreads();

  if (tid < 128) {
    const int r = tid >> 5, d = tid & 31;
    const int sl = d >> 2, c = d & 3;
    float val = 0.f;
#pragma unroll
    for (int w = 0; w < 4; ++w) val += pvred[(((w << 3) + sl) * 4 + r) * 4 + c];
    float dn = (r == 0) ? dnm0 : (r == 1) ? dnm1 : (r == 2) ? dnm2 : dnm3;
    val /= dn;
    AO[(head * HD + d) * NTOK + n0 + r] = val;  // [C][N] for proj GEMM
  }
}

// ---- kernel 5: GroupNorm stats (32 groups of 8 ch x 4096 = 32768 vals) ----

__global__ __launch_bounds__(256) void gn_stats(const float* __restrict__ O,
                                                float* __restrict__ ST) {
  const int g = blockIdx.x, tid = threadIdx.x;
  const float4* p4 = (const float4*)(O + g * 32768);
  float s = 0.f, ss = 0.f;
  for (int i = tid; i < 8192; i += 256) {
    float4 v = p4[i];
    s += (v.x + v.y) + (v.z + v.w);
    ss += (v.x * v.x + v.y * v.y) + (v.z * v.z + v.w * v.w);
  }
#pragma unroll
  for (int m = 1; m < 64; m <<= 1) {
    s += __shfl_xor(s, m);
    ss += __shfl_xor(ss, m);
  }
  __shared__ float rs[4], rss[4];
  if ((tid & 63) == 0) { rs[tid >> 6] = s; rss[tid >> 6] = ss; }
  __syncthreads();
  if (tid == 0) {
    float S = rs[0] + rs[1] + rs[2] + rs[3];
    float SS = rss[0] + rss[1] + rss[2] + rss[3];
    float mean = S * (1.f / 32768.f);
    float var = SS * (1.f / 32768.f) - mean * mean;
    ST[g * 2] = mean;
    ST[g * 2 + 1] = rsqrtf(var + 1e-6f);
  }
}

// ---- kernel 6: GroupNorm apply (in place on d_out) ------------------------
// Indexes FLOAT4s: total 1048576/4 = 262144 -> grid 1024 x 256.

__global__ __launch_bounds__(256) void gn_apply(float* __restrict__ O,
                                                const float* __restrict__ ST,
                                                const float* __restrict__ gamma,
                                                const float* __restrict__ beta) {
  const int i4 = blockIdx.x * 256 + threadIdx.x;  // float4 index
  const int c = i4 >> 10, g = c >> 3;
  const float a = ST[g * 2 + 1] * gamma[c];
  const float b = beta[c] - ST[g * 2] * a;
  float4 v = *(float4*)(O + (i4 << 2));
  v.x = v.x * a + b; v.y = v.y * a + b; v.z = v.z * a + b; v.w = v.w * a + b;
  *(float4*)(O + (i4 << 2)) = v;
}

// ---- launch ---------------------------------------------------------------

extern "C" void kernel_launch(void* const* d_in, const int* in_sizes, int n_in,
                              void* d_out, int out_size, void* d_ws,
                              size_t ws_size, hipStream_t stream) {
  const float* x = (const float*)d_in[0];       // [256][4096]
  const float* w_qkv = (const float*)d_in[1];   // [768][256]
  const float* w_proj = (const float*)d_in[2];  // [256][256]
  const float* gamma = (const float*)d_in[3];   // [256]
  const float* beta = (const float*)d_in[4];    // [256]
  float* out = (float*)d_out;                   // [256][4096]

  float* Q = (float*)d_ws;          // [8][4096][32]
  float* KT = Q + 1048576;          // [8][32][4096]  (transposed)
  float* V = KT + 1048576;          // [8][4096][32]
  float* AO = V + 1048576;          // [256][4096]
  float* ST = AO + 1048576;         // [32][2]

  gemm_k256<true><<<dim3(64, 12), 256, 0, stream>>>(w_qkv, x, Q, KT, V);
  l2norm_q<<<4096, 256, 0, stream>>>(Q);
  l2norm_kt<<<dim3(16, 8), 256, 0, stream>>>(KT);
  attn_kernel<<<8192, 256, 0, stream>>>(Q, KT, V, AO);
  gemm_k256<false><<<dim3(64, 4), 256, 0, stream>>>(w_proj, AO, out, nullptr, nullptr);
  gn_stats<<<32, 256, 0, stream>>>(out, ST);
  gn_apply<<<1024, 256, 0, stream>>>(out, ST, gamma, beta);
}

// Round 13
// 452.756 us; speedup vs baseline: 1.1276x; 1.1276x over previous
//
#include <hip/hip_runtime.h>

// ---------------------------------------------------------------------------
// LowFreqSparseAttention: qkv 1x1conv -> l2norm(q,k) -> S=QK^T*scale ->
// top-k(k=N/2) mask -> softmax -> PV -> proj 1x1conv -> GroupNorm(32 groups).
// B=1, C=256, H=W=64 -> N=4096, 8 heads, hd=32, k_sel=2048.
//
// R26 = R19 base + fp16-K dot2 PHASE 2 (convert-once).
// R25 post-mortem (twice-confirmed lesson): dot2 only pays when operands
// are ALREADY fp16 -- per-use conversion cancels the savings (R25: 16
// saved FMA repurchased as 16 converts, 436us vs R19's 411).
// Phase 2 satisfies convert-once: K is packed to fp16 d-pairs UPSTREAM.
//  * l2norm_kt now writes packed fp16 pairs IN PLACE over KT's first 16
//    rows (K16[h][d2][n] = (K[2d2][n],K[2d2+1][n]) fp16). Aliasing is
//    column-local; each thread loads all 32 d before storing -> safe.
//  * phase1 packs the 4 q rows into fp16 d-pairs in LDS (once/block).
//  * phase2: 16 d2-iters x {4 coalesced b128 K-pair loads + 4 broadcast
//    b32 q-pair reads + 64 v_dot2_f32_f16} ~= 1216 insts vs ~2368.
//    fp32 accumulate; score err ~5e-4 << u8 weight quantization.
//    Selection exact on computed kr (self-consistent). K L2 traffic halves.
//  * phases 3/4/5 = R19 verbatim (u8 weights, scalar PV).
// Predict: attn ~340-370, total ~440-470, VALU ~75-78, occ ~50,
// FETCH ~8MB, absmax <= 0.0313.
// Falsif. (pre-committed): absmax fail or attn >= 400 -> revert R19,
// declare structural floor.
// ---------------------------------------------------------------------------

#define NTOK 4096
#define HD 32
#define NHEADS 8
#define KSEL 2048
#define SCALE 0.17677669529663689f   // 32^-0.5  (folded into l2norm_q)
#define LOG2C 7.73937f               // log2(255 / e^0.1767767)

typedef __fp16 f16x2 __attribute__((ext_vector_type(2)));

#define USE_DOT2 (__has_builtin(__builtin_amdgcn_fdot2) && \
                  __has_builtin(__builtin_amdgcn_cvt_pkrtz))

// ---- helpers --------------------------------------------------------------

__device__ __forceinline__ unsigned fkey(float f) {
  unsigned b = __float_as_uint(f);
  return (b & 0x80000000u) ? ~b : (b | 0x80000000u);
}
__device__ __forceinline__ float unfkey(unsigned k) {
  unsigned b = (k & 0x80000000u) ? (k ^ 0x80000000u) : ~k;
  return __uint_as_float(b);
}
__device__ __forceinline__ unsigned rfl_u(unsigned x) {  // force SGPR
  return __builtin_amdgcn_readfirstlane(x);
}
__device__ __forceinline__ f16x2 asv2h(unsigned u) {
  union { unsigned u; f16x2 h; } c; c.u = u; return c.h;
}
__device__ __forceinline__ unsigned asu32(f16x2 h) {
  union { f16x2 h; unsigned u; } c; c.h = h; return c.u;
}
// regula-falsi probe in key space, clamped to (klo, khi]
__device__ __forceinline__ unsigned probe_rf(unsigned klo, unsigned khi,
                                             float xlo, float xhi,
                                             int clo, int chi) {
  float t = xlo + (xhi - xlo) * ((float)(clo - KSEL) / (float)(clo - chi));
  unsigned k = fkey(t);
  if (k <= klo) k = klo + 1u;
  if (k > khi) k = khi;
  return k;
}

// ---- kernel 1/4: GEMM  C[M][4096] = A[M][256] * B[256][4096] --------------
// SCATTER: M=768 -> Q [h][n][d], KT [h][d][n] (transposed!), V [h][n][d].
// else:    M=256 -> plain row-major C0.

template <bool SCATTER>
__global__ __launch_bounds__(256) void gemm_k256(
    const float* __restrict__ A, const float* __restrict__ B,
    float* __restrict__ C0, float* __restrict__ C1, float* __restrict__ C2) {
  __shared__ float Wt[64][17];   // +1 pad: avoid 16-way bank conflict
  __shared__ float Xt[16][64];

  const int tid = threadIdx.x;
  const int tx = tid & 15, ty = tid >> 4;
  const int o0 = blockIdx.y * 64, n0 = blockIdx.x * 64;

  const int wr = tid >> 2, wc = (tid & 3) << 2;   // W-tile 64x16 loader
  const int xr = tid >> 4, xc = (tid & 15) << 2;  // X-tile 16x64 loader

  float4 acc[4];
#pragma unroll
  for (int i = 0; i < 4; ++i) acc[i] = make_float4(0.f, 0.f, 0.f, 0.f);

  for (int k0 = 0; k0 < 256; k0 += 16) {
    float4 wv = *(const float4*)(A + (o0 + wr) * 256 + k0 + wc);
    float4 xv = *(const float4*)(B + (k0 + xr) * 4096 + n0 + xc);
    Wt[wr][wc + 0] = wv.x; Wt[wr][wc + 1] = wv.y;
    Wt[wr][wc + 2] = wv.z; Wt[wr][wc + 3] = wv.w;
    *(float4*)&Xt[xr][xc] = xv;
    __syncthreads();
#pragma unroll
    for (int kk = 0; kk < 16; ++kk) {
      float4 b = *(const float4*)&Xt[kk][tx << 2];
#pragma unroll
      for (int i = 0; i < 4; ++i) {
        float a = Wt[(ty << 2) + i][kk];
        acc[i].x += a * b.x; acc[i].y += a * b.y;
        acc[i].z += a * b.z; acc[i].w += a * b.w;
      }
    }
    __syncthreads();
  }

  if (SCATTER) {
#pragma unroll
    for (int i = 0; i < 4; ++i) {
      int o = o0 + (ty << 2) + i;
      int which = o >> 8, rem = o & 255;
      int h = rem >> 5, d = rem & 31;
      int n = n0 + (tx << 2);
      if (which == 1) {
        // KT[h][d][n..n+3]: contiguous float4
        *(float4*)(C1 + h * (HD * NTOK) + d * NTOK + n) = acc[i];
      } else {
        float* dst = (which == 0) ? C0 : C2;
        int base = h * (NTOK * HD) + d;
        dst[base + (n + 0) * HD] = acc[i].x;
        dst[base + (n + 1) * HD] = acc[i].y;
        dst[base + (n + 2) * HD] = acc[i].z;
        dst[base + (n + 3) * HD] = acc[i].w;
      }
    }
  } else {
#pragma unroll
    for (int i = 0; i < 4; ++i) {
      int o = o0 + (ty << 2) + i;
      *(float4*)(C0 + o * 4096 + n0 + (tx << 2)) = acc[i];
    }
  }
}

// ---- kernel 2a: l2norm Q rows [h][n][32], folds SCALE ---------------------

__global__ __launch_bounds__(256) void l2norm_q(float* __restrict__ Q) {
  const int tid = threadIdx.x;
  const int p = blockIdx.x * 8 + (tid >> 5);  // (head*4096+n) row index
  const int d = tid & 31;
  const int idx = p * HD + d;
  float v = Q[idx];
  float ss = v * v;
#pragma unroll
  for (int m = 16; m >= 1; m >>= 1) ss += __shfl_xor(ss, m, 32);
  float nrm = sqrtf(ss);
  Q[idx] = v * SCALE / fmaxf(nrm, 1e-12f);
}

// ---- kernel 2b: l2norm KT columns + fp16 d-pair pack (in place) -----------
// Reads KT[h][d][n] (fp32, all 32 d at fixed n), normalizes, writes packed
// fp16 pairs K16[h][d2][n] = (k[2d2],k[2d2+1]) over KT's first 16 rows.
// Aliasing is column-local (thread reads its column fully before storing).

__global__ __launch_bounds__(256) void l2norm_kt_pack(float* __restrict__ KT) {
  const int n = blockIdx.x * 256 + threadIdx.x;
  float* P = KT + blockIdx.y * (HD * NTOK) + n;
  float v[HD];
  float ss = 0.f;
#pragma unroll
  for (int d = 0; d < HD; ++d) {
    v[d] = P[d * NTOK];          // coalesced across lanes
    ss += v[d] * v[d];
  }
  float inv = 1.f / fmaxf(sqrtf(ss), 1e-12f);
  unsigned* O = (unsigned*)P;    // in-place: rows 0..15 as pair words
#pragma unroll
  for (int d2 = 0; d2 < 16; ++d2) {
#if USE_DOT2
    O[d2 * NTOK] = asu32(
        __builtin_amdgcn_cvt_pkrtz(v[2 * d2] * inv, v[2 * d2 + 1] * inv));
#else
    f16x2 p; p[0] = (__fp16)(v[2 * d2] * inv); p[1] = (__fp16)(v[2 * d2 + 1] * inv);
    O[d2 * NTOK] = asu32(p);
#endif
  }
}

// ---- kernel 3: fused attention (4 rows per block, column-partitioned) -----
// phase1: stage 4 q rows (fp32) + pack fp16 q d-pairs into LDS (once).
// phase2: thread tid owns cols {g*1024 + tid*4 + t}; 16 d2-iters of
//         {4 coalesced b128 K-pair loads + 4 broadcast b32 q-pair reads +
//          64 v_dot2_f32_f16} -> kr[4][16] fp32.
// phase3: hybrid selection (R19 window: RF while it<8 && width>65536, then
//         ulp bisection). Counts readfirstlane'd -> state SALU/SGPR;
//         per-row done-guards skip converged ballots.
// phase4: u8 weights packed 4 rows/col -> ONE ds_write_b128 per 4 cols;
//         exact integer denominators, block-reduced.  (R19 verbatim)
// phase5: PV scalar u8 (R19 verbatim, unroll 4).

__global__ __launch_bounds__(256, 5) void attn_kernel(
    const float* __restrict__ Q, const float* __restrict__ KT,
    const float* __restrict__ V, float* __restrict__ AO) {
  __shared__ __align__(16) unsigned char wtsT[NTOK][4];   // 16 KB, [m][row]
  __shared__ float qs[128];
  __shared__ unsigned qs2u[4][16];                        // fp16 q d-pairs
  __shared__ float pvred[4 * 8 * 4 * 4];                  // 2 KB
  __shared__ unsigned ired[2][4][2];                      // bisection dbuf
  __shared__ unsigned dred[4][4];                         // denom partials

  const int tid = threadIdx.x;
  const int wv = tid >> 6, lane = tid & 63;
  const int head = blockIdx.x & 7;          // head == blockIdx%8 -> XCD-pinned
  const int n0 = (blockIdx.x >> 3) << 2;

  const float* Qh = Q + head * (NTOK * HD);
  const float* KTh = KT + head * (HD * NTOK);
  const float* Vh = V + head * (NTOK * HD);

  // phase 1: stage the block's 4 q rows (already *SCALE from l2norm_q),
  // then pack fp16 d-pairs (once per block).
  if (tid < 128) qs[tid] = Qh[n0 * HD + tid];
  __syncthreads();
  if (tid < 64) {
    const int r = tid >> 4, d2 = tid & 15;
#if USE_DOT2
    qs2u[r][d2] = asu32(__builtin_amdgcn_cvt_pkrtz(
        qs[r * HD + (d2 << 1)], qs[r * HD + (d2 << 1) + 1]));
#else
    f16x2 p; p[0] = (__fp16)qs[r * HD + (d2 << 1)];
    p[1] = (__fp16)qs[r * HD + (d2 << 1) + 1];
    qs2u[r][d2] = asu32(p);
#endif
  }
  __syncthreads();

  // phase 2: kr[r][g*4+t] = score(row r, col g*1024 + tid*4 + t) via dot2
  // over d-pairs. Each K pair-word read by exactly ONE thread of the block.
  float kr[4][16];
#pragma unroll
  for (int r = 0; r < 4; ++r)
#pragma unroll
    for (int j = 0; j < 16; ++j) kr[r][j] = 0.f;

  const int cb = tid << 2;
  const unsigned* k16 = (const unsigned*)KTh + cb;   // [16][NTOK] pair words
#pragma unroll 1
  for (int d2 = 0; d2 < 16; ++d2) {
    const unsigned* kp = k16 + d2 * NTOK;
    const uint4 kv0 = *(const uint4*)(kp);
    const uint4 kv1 = *(const uint4*)(kp + 1024);
    const uint4 kv2 = *(const uint4*)(kp + 2048);
    const uint4 kv3 = *(const uint4*)(kp + 3072);
    const unsigned qu0 = qs2u[0][d2], qu1 = qs2u[1][d2];
    const unsigned qu2 = qs2u[2][d2], qu3 = qs2u[3][d2];
#if USE_DOT2
    const f16x2 q0 = asv2h(qu0), q1 = asv2h(qu1);
    const f16x2 q2 = asv2h(qu2), q3 = asv2h(qu3);
#define DOT16(r, qv)                                                         \
    kr[r][0]  = __builtin_amdgcn_fdot2(qv, asv2h(kv0.x), kr[r][0],  false);  \
    kr[r][1]  = __builtin_amdgcn_fdot2(qv, asv2h(kv0.y), kr[r][1],  false);  \
    kr[r][2]  = __builtin_amdgcn_fdot2(qv, asv2h(kv0.z), kr[r][2],  false);  \
    kr[r][3]  = __builtin_amdgcn_fdot2(qv, asv2h(kv0.w), kr[r][3],  false);  \
    kr[r][4]  = __builtin_amdgcn_fdot2(qv, asv2h(kv1.x), kr[r][4],  false);  \
    kr[r][5]  = __builtin_amdgcn_fdot2(qv, asv2h(kv1.y), kr[r][5],  false);  \
    kr[r][6]  = __builtin_amdgcn_fdot2(qv, asv2h(kv1.z), kr[r][6],  false);  \
    kr[r][7]  = __builtin_amdgcn_fdot2(qv, asv2h(kv1.w), kr[r][7],  false);  \
    kr[r][8]  = __builtin_amdgcn_fdot2(qv, asv2h(kv2.x), kr[r][8],  false);  \
    kr[r][9]  = __builtin_amdgcn_fdot2(qv, asv2h(kv2.y), kr[r][9],  false);  \
    kr[r][10] = __builtin_amdgcn_fdot2(qv, asv2h(kv2.z), kr[r][10], false);  \
    kr[r][11] = __builtin_amdgcn_fdot2(qv, asv2h(kv2.w), kr[r][11], false);  \
    kr[r][12] = __builtin_amdgcn_fdot2(qv, asv2h(kv3.x), kr[r][12], false);  \
    kr[r][13] = __builtin_amdgcn_fdot2(qv, asv2h(kv3.y), kr[r][13], false);  \
    kr[r][14] = __builtin_amdgcn_fdot2(qv, asv2h(kv3.z), kr[r][14], false);  \
    kr[r][15] = __builtin_amdgcn_fdot2(qv, asv2h(kv3.w), kr[r][15], false);
    DOT16(0, q0) DOT16(1, q1) DOT16(2, q2) DOT16(3, q3)
#undef DOT16
#else
    // fallback: decode pairs and FMA (compile insurance; fdot2 proven on HW)
#define DOTF(r, qu)                                                          \
    {                                                                        \
      const f16x2 qq = asv2h(qu);                                            \
      const float qa = (float)qq[0], qb = (float)qq[1];                      \
      const unsigned kk[16] = {kv0.x, kv0.y, kv0.z, kv0.w, kv1.x, kv1.y,     \
                               kv1.z, kv1.w, kv2.x, kv2.y, kv2.z, kv2.w,     \
                               kv3.x, kv3.y, kv3.z, kv3.w};                  \
      _Pragma("unroll")                                                      \
      for (int j = 0; j < 16; ++j) {                                         \
        const f16x2 kh = asv2h(kk[j]);                                       \
        kr[r][j] += qa * (float)kh[0] + qb * (float)kh[1];                   \
      }                                                                      \
    }
    DOTF(0, qu0) DOTF(1, qu1) DOTF(2, qu2) DOTF(3, qu3)
#undef DOTF
#endif
  }

  // phase 3: hybrid selection per row (R19 schedule). Bracket invariant
  // (key space): count(klo) >= KSEL, answer in [klo, khi]. RF probe while
  // it<8 && width>65536; ulp midpoint after. Exit on count==KSEL (kept set
  // == top-k of the COMPUTED scores; ties make the count skip KSEL so
  // ==KSEL is tie-free) or klo==khi (exact kth key).
  // |scores| <= 0.1768 < 0.25, so anchors (-0.25 -> 4096, +0.25 -> 0).
  // State block-uniform; counts readfirstlane'd -> SGPR/SALU resident.
  unsigned klo0 = 0x417FFFFFu, khi0 = 0xBE800000u;  // fkey(-.25), fkey(.25)
  unsigned klo1 = 0x417FFFFFu, khi1 = 0xBE800000u;
  unsigned klo2 = 0x417FFFFFu, khi2 = 0xBE800000u;
  unsigned klo3 = 0x417FFFFFu, khi3 = 0xBE800000u;
  float xlo0 = -0.25f, xhi0 = 0.25f, xlo1 = -0.25f, xhi1 = 0.25f;
  float xlo2 = -0.25f, xhi2 = 0.25f, xlo3 = -0.25f, xhi3 = 0.25f;
  int clo0 = NTOK, chi0 = 0, clo1 = NTOK, chi1 = 0;
  int clo2 = NTOK, chi2 = 0, clo3 = NTOK, chi3 = 0;
  bool dn0 = false, dn1 = false, dn2 = false, dn3 = false;
  int slot = 0;
#pragma unroll 1
  for (int it = 0; it < 40; ++it) {
    unsigned m0 = dn0 ? klo0
        : ((it < 8 && (khi0 - klo0) > 65536u)
               ? rfl_u(probe_rf(klo0, khi0, xlo0, xhi0, clo0, chi0))
               : klo0 + ((khi0 - klo0 + 1u) >> 1));
    unsigned m1 = dn1 ? klo1
        : ((it < 8 && (khi1 - klo1) > 65536u)
               ? rfl_u(probe_rf(klo1, khi1, xlo1, xhi1, clo1, chi1))
               : klo1 + ((khi1 - klo1 + 1u) >> 1));
    unsigned m2 = dn2 ? klo2
        : ((it < 8 && (khi2 - klo2) > 65536u)
               ? rfl_u(probe_rf(klo2, khi2, xlo2, xhi2, clo2, chi2))
               : klo2 + ((khi2 - klo2 + 1u) >> 1));
    unsigned m3 = dn3 ? klo3
        : ((it < 8 && (khi3 - klo3) > 65536u)
               ? rfl_u(probe_rf(klo3, khi3, xlo3, xhi3, clo3, chi3))
               : klo3 + ((khi3 - klo3 + 1u) >> 1));
    unsigned c0 = 0, c1 = 0, c2 = 0, c3 = 0;
    if (!dn0) {
      const float f0 = unfkey(m0);
#pragma unroll
      for (int j = 0; j < 16; ++j) c0 += __popcll(__ballot(kr[0][j] >= f0));
    }
    if (!dn1) {
      const float f1 = unfkey(m1);
#pragma unroll
      for (int j = 0; j < 16; ++j) c1 += __popcll(__ballot(kr[1][j] >= f1));
    }
    if (!dn2) {
      const float f2 = unfkey(m2);
#pragma unroll
      for (int j = 0; j < 16; ++j) c2 += __popcll(__ballot(kr[2][j] >= f2));
    }
    if (!dn3) {
      const float f3 = unfkey(m3);
#pragma unroll
      for (int j = 0; j < 16; ++j) c3 += __popcll(__ballot(kr[3][j] >= f3));
    }
    if (lane == 0) {
      ired[slot][wv][0] = c0 | (c1 << 16);
      ired[slot][wv][1] = c2 | (c3 << 16);
    }
    __syncthreads();
    unsigned a01 = rfl_u(ired[slot][0][0] + ired[slot][1][0] +
                         ired[slot][2][0] + ired[slot][3][0]);
    unsigned a23 = rfl_u(ired[slot][0][1] + ired[slot][1][1] +
                         ired[slot][2][1] + ired[slot][3][1]);
    slot ^= 1;
    int C0 = (int)(a01 & 0xFFFFu), C1 = (int)(a01 >> 16);
    int C2 = (int)(a23 & 0xFFFFu), C3 = (int)(a23 >> 16);
#define BUPD(C, klo, khi, xlo, xhi, clo, chi, dn, mk)                        \
    if (!dn) {                                                               \
      if (C == KSEL) { klo = mk; dn = true; }                                \
      else if (C > KSEL) { klo = mk; xlo = unfkey(mk); clo = C; }            \
      else { khi = mk - 1u; xhi = unfkey(mk); chi = C; }                     \
      if (klo >= khi) dn = true;                                             \
    }
    BUPD(C0, klo0, khi0, xlo0, xhi0, clo0, chi0, dn0, m0)
    BUPD(C1, klo1, khi1, xlo1, xhi1, clo1, chi1, dn1, m1)
    BUPD(C2, klo2, khi2, xlo2, xhi2, clo2, chi2, dn2, m2)
    BUPD(C3, klo3, khi3, xlo3, xhi3, clo3, chi3, dn3, m3)
#undef BUPD
    if (dn0 && dn1 && dn2 && dn3) break;   // uniform across block
  }
  const float tf0 = unfkey(klo0), tf1 = unfkey(klo1);
  const float tf2 = unfkey(klo2), tf3 = unfkey(klo3);

  // phase 4: u8 weights, 4 rows packed per column, b128 per 4 columns.
  // u = rint(exp(s) * 255/e^smax) in [179,255] kept, 0 masked. (R19)
  unsigned id0 = 0, id1 = 0, id2 = 0, id3 = 0;
#pragma unroll
  for (int g = 0; g < 4; ++g) {
    unsigned pk[4];
#pragma unroll
    for (int t = 0; t < 4; ++t) {
      const int j = (g << 2) + t;
      float s0 = kr[0][j], s1 = kr[1][j], s2 = kr[2][j], s3 = kr[3][j];
      unsigned u0 = (s0 >= tf0) ? (unsigned)rintf(exp2f(__builtin_fmaf(s0, 1.44269504f, LOG2C))) : 0u;
      unsigned u1 = (s1 >= tf1) ? (unsigned)rintf(exp2f(__builtin_fmaf(s1, 1.44269504f, LOG2C))) : 0u;
      unsigned u2 = (s2 >= tf2) ? (unsigned)rintf(exp2f(__builtin_fmaf(s2, 1.44269504f, LOG2C))) : 0u;
      unsigned u3 = (s3 >= tf3) ? (unsigned)rintf(exp2f(__builtin_fmaf(s3, 1.44269504f, LOG2C))) : 0u;
      id0 += u0; id1 += u1; id2 += u2; id3 += u3;
      pk[t] = u0 | (u1 << 8) | (u2 << 16) | (u3 << 24);
    }
    const int col = (g << 10) + cb;            // addr = col*4, 16B-aligned
    *(uint4*)&wtsT[col][0] = make_uint4(pk[0], pk[1], pk[2], pk[3]);
  }
  // exact integer denominators: wave-reduce then cross-wave sum
#pragma unroll
  for (int s = 1; s < 64; s <<= 1) {
    id0 += __shfl_xor(id0, s); id1 += __shfl_xor(id1, s);
    id2 += __shfl_xor(id2, s); id3 += __shfl_xor(id3, s);
  }
  if (lane == 0) *(uint4*)&dred[wv][0] = make_uint4(id0, id1, id2, id3);
  __syncthreads();  // wtsT + dred visible to all
  const float dnm0 = (float)(dred[0][0] + dred[1][0] + dred[2][0] + dred[3][0]);
  const float dnm1 = (float)(dred[0][1] + dred[1][1] + dred[2][1] + dred[3][1]);
  const float dnm2 = (float)(dred[0][2] + dred[1][2] + dred[2][2] + dred[3][2]);
  const float dnm3 = (float)(dred[0][3] + dred[1][3] + dred[2][3] + dred[3][3]);

  // phase 5: PV with integer weights (R19). wave wv covers m in
  // [wv*1024, +1024); unroll 4.
  const int slot5 = lane & 7, mg = lane >> 3;
  const int mbase = wv << 10;
  float av[4][4];
#pragma unroll
  for (int r = 0; r < 4; ++r)
#pragma unroll
    for (int c = 0; c < 4; ++c) av[r][c] = 0.f;

#pragma unroll 4
  for (int ii = 0; ii < 128; ++ii) {
    const int m = mbase + (ii << 3) + mg;
    unsigned wq = *(const unsigned*)&wtsT[m][0];   // one b32: rows 0..3
    float4 v = *(const float4*)(Vh + m * HD + (slot5 << 2));
    float w0 = (float)(wq & 0xFFu);          // v_cvt_f32_ubyte0
    float w1 = (float)((wq >> 8) & 0xFFu);   // v_cvt_f32_ubyte1
    float w2 = (float)((wq >> 16) & 0xFFu);  // v_cvt_f32_ubyte2
    float w3 = (float)(wq >> 24);            // v_cvt_f32_ubyte3
    av[0][0] += w0 * v.x; av[0][1] += w0 * v.y; av[0][2] += w0 * v.z; av[0][3] += w0 * v.w;
    av[1][0] += w1 * v.x; av[1][1] += w1 * v.y; av[1][2] += w1 * v.z; av[1][3] += w1 * v.w;
    av[2][0] += w2 * v.x; av[2][1] += w2 * v.y; av[2][2] += w2 * v.z; av[2][3] += w2 * v.w;
    av[3][0] += w3 * v.x; av[3][1] += w3 * v.y; av[3][2] += w3 * v.z; av[3][3] += w3 * v.w;
  }
  // reduce over mg (lane bits 3..5)
#pragma unroll
  for (int r = 0; r < 4; ++r)
#pragma unroll
    for (int c = 0; c < 4; ++c) {
      float x = av[r][c];
      x += __shfl_xor(x, 8); x += __shfl_xor(x, 16); x += __shfl_xor(x, 32);
      av[r][c] = x;
    }
  if (mg == 0) {
#pragma unroll
    for (int r = 0; r < 4; ++r)
#pragma unroll
      for (int c = 0; c < 4; ++c)
        pvred[(((wv << 3) + slot5) * 4 + r) * 4 + c] = av[r][c];
  }
  __syncthreads();

  if (tid < 128) {
    const int r = tid >> 5, d = tid & 31;
    const int sl = d >> 2, c = d & 3;
    float val = 0.f;
#pragma unroll
    for (int w = 0; w < 4; ++w) val += pvred[(((w << 3) + sl) * 4 + r) * 4 + c];
    float dn = (r == 0) ? dnm0 : (r == 1) ? dnm1 : (r == 2) ? dnm2 : dnm3;
    val /= dn;
    AO[(head * HD + d) * NTOK + n0 + r] = val;  // [C][N] for proj GEMM
  }
}

// ---- kernel 5: GroupNorm stats (32 groups of 8 ch x 4096 = 32768 vals) ----

__global__ __launch_bounds__(256) void gn_stats(const float* __restrict__ O,
                                                float* __restrict__ ST) {
  const int g = blockIdx.x, tid = threadIdx.x;
  const float4* p4 = (const float4*)(O + g * 32768);
  float s = 0.f, ss = 0.f;
  for (int i = tid; i < 8192; i += 256) {
    float4 v = p4[i];
    s += (v.x + v.y) + (v.z + v.w);
    ss += (v.x * v.x + v.y * v.y) + (v.z * v.z + v.w * v.w);
  }
#pragma unroll
  for (int m = 1; m < 64; m <<= 1) {
    s += __shfl_xor(s, m);
    ss += __shfl_xor(ss, m);
  }
  __shared__ float rs[4], rss[4];
  if ((tid & 63) == 0) { rs[tid >> 6] = s; rss[tid >> 6] = ss; }
  __syncthreads();
  if (tid == 0) {
    float S = rs[0] + rs[1] + rs[2] + rs[3];
    float SS = rss[0] + rss[1] + rss[2] + rss[3];
    float mean = S * (1.f / 32768.f);
    float var = SS * (1.f / 32768.f) - mean * mean;
    ST[g * 2] = mean;
    ST[g * 2 + 1] = rsqrtf(var + 1e-6f);
  }
}

// ---- kernel 6: GroupNorm apply (in place on d_out) ------------------------
// Indexes FLOAT4s: total 1048576/4 = 262144 -> grid 1024 x 256.

__global__ __launch_bounds__(256) void gn_apply(float* __restrict__ O,
                                                const float* __restrict__ ST,
                                                const float* __restrict__ gamma,
                                                const float* __restrict__ beta) {
  const int i4 = blockIdx.x * 256 + threadIdx.x;  // float4 index
  const int c = i4 >> 10, g = c >> 3;
  const float a = ST[g * 2 + 1] * gamma[c];
  const float b = beta[c] - ST[g * 2] * a;
  float4 v = *(float4*)(O + (i4 << 2));
  v.x = v.x * a + b; v.y = v.y * a + b; v.z = v.z * a + b; v.w = v.w * a + b;
  *(float4*)(O + (i4 << 2)) = v;
}

// ---- launch ---------------------------------------------------------------

extern "C" void kernel_launch(void* const* d_in, const int* in_sizes, int n_in,
                              void* d_out, int out_size, void* d_ws,
                              size_t ws_size, hipStream_t stream) {
  const float* x = (const float*)d_in[0];       // [256][4096]
  const float* w_qkv = (const float*)d_in[1];   // [768][256]
  const float* w_proj = (const float*)d_in[2];  // [256][256]
  const float* gamma = (const float*)d_in[3];   // [256]
  const float* beta = (const float*)d_in[4];    // [256]
  float* out = (float*)d_out;                   // [256][4096]

  float* Q = (float*)d_ws;          // [8][4096][32]
  float* KT = Q + 1048576;          // [8][32][4096] fp32 -> fp16 pairs in place
  float* V = KT + 1048576;          // [8][4096][32]
  float* AO = V + 1048576;          // [256][4096]
  float* ST = AO + 1048576;         // [32][2]

  gemm_k256<true><<<dim3(64, 12), 256, 0, stream>>>(w_qkv, x, Q, KT, V);
  l2norm_q<<<4096, 256, 0, stream>>>(Q);
  l2norm_kt_pack<<<dim3(16, 8), 256, 0, stream>>>(KT);
  attn_kernel<<<8192, 256, 0, stream>>>(Q, KT, V, AO);
  gemm_k256<false><<<dim3(64, 4), 256, 0, stream>>>(w_proj, AO, out, nullptr, nullptr);
  gn_stats<<<32, 256, 0, stream>>>(out, ST);
  gn_apply<<<1024, 256, 0, stream>>>(out, ST, gamma, beta);
}

// Round 14
// 449.848 us; speedup vs baseline: 1.1349x; 1.0065x over previous
//
#include <hip/hip_runtime.h>

// ---------------------------------------------------------------------------
// LowFreqSparseAttention: qkv 1x1conv -> l2norm(q,k) -> S=QK^T*scale ->
// top-k(k=N/2) mask -> softmax -> PV -> proj 1x1conv -> GroupNorm(32 groups).
// B=1, C=256, H=W=64 -> N=4096, 8 heads, hd=32, k_sel=2048.
//
// R27 = R26 (371us attn -- fp16-K dot2 phase2, WIN) with ONE change:
// __launch_bounds__(256,5) -> (256,4) on attn_kernel.
// R26 post-mortem: WRITE exploded 20->168MB (= ~20 dwords/thread scratch
// spill): phase2's peak (kr 64 + 16 kv pair-words + addr) brushes the
// 5-wave arch-VGPR cap (102). Measured occupancy is 4 waves/SIMD EITHER
// WAY (total footprint decides, not the cap) -- so the 5-wave request
// bought nothing and forced the spill. Cap 128 keeps kv resident.
// Predict: WRITE ~4MB, FETCH ~9.5MB, VGPR ~60-80, occ ~51 flat,
// attn ~335-355, total ~415-440.
// Tripwire: occ ~38% => total regs crossed 128 -> revert. WRITE still
// ~168MB => spill is scheduling-induced -> split kv loads 2+2.
// ---------------------------------------------------------------------------

#define NTOK 4096
#define HD 32
#define NHEADS 8
#define KSEL 2048
#define SCALE 0.17677669529663689f   // 32^-0.5  (folded into l2norm_q)
#define LOG2C 7.73937f               // log2(255 / e^0.1767767)

typedef __fp16 f16x2 __attribute__((ext_vector_type(2)));

#define USE_DOT2 (__has_builtin(__builtin_amdgcn_fdot2) && \
                  __has_builtin(__builtin_amdgcn_cvt_pkrtz))

// ---- helpers --------------------------------------------------------------

__device__ __forceinline__ unsigned fkey(float f) {
  unsigned b = __float_as_uint(f);
  return (b & 0x80000000u) ? ~b : (b | 0x80000000u);
}
__device__ __forceinline__ float unfkey(unsigned k) {
  unsigned b = (k & 0x80000000u) ? (k ^ 0x80000000u) : ~k;
  return __uint_as_float(b);
}
__device__ __forceinline__ unsigned rfl_u(unsigned x) {  // force SGPR
  return __builtin_amdgcn_readfirstlane(x);
}
__device__ __forceinline__ f16x2 asv2h(unsigned u) {
  union { unsigned u; f16x2 h; } c; c.u = u; return c.h;
}
__device__ __forceinline__ unsigned asu32(f16x2 h) {
  union { f16x2 h; unsigned u; } c; c.h = h; return c.u;
}
// regula-falsi probe in key space, clamped to (klo, khi]
__device__ __forceinline__ unsigned probe_rf(unsigned klo, unsigned khi,
                                             float xlo, float xhi,
                                             int clo, int chi) {
  float t = xlo + (xhi - xlo) * ((float)(clo - KSEL) / (float)(clo - chi));
  unsigned k = fkey(t);
  if (k <= klo) k = klo + 1u;
  if (k > khi) k = khi;
  return k;
}

// ---- kernel 1/4: GEMM  C[M][4096] = A[M][256] * B[256][4096] --------------
// SCATTER: M=768 -> Q [h][n][d], KT [h][d][n] (transposed!), V [h][n][d].
// else:    M=256 -> plain row-major C0.

template <bool SCATTER>
__global__ __launch_bounds__(256) void gemm_k256(
    const float* __restrict__ A, const float* __restrict__ B,
    float* __restrict__ C0, float* __restrict__ C1, float* __restrict__ C2) {
  __shared__ float Wt[64][17];   // +1 pad: avoid 16-way bank conflict
  __shared__ float Xt[16][64];

  const int tid = threadIdx.x;
  const int tx = tid & 15, ty = tid >> 4;
  const int o0 = blockIdx.y * 64, n0 = blockIdx.x * 64;

  const int wr = tid >> 2, wc = (tid & 3) << 2;   // W-tile 64x16 loader
  const int xr = tid >> 4, xc = (tid & 15) << 2;  // X-tile 16x64 loader

  float4 acc[4];
#pragma unroll
  for (int i = 0; i < 4; ++i) acc[i] = make_float4(0.f, 0.f, 0.f, 0.f);

  for (int k0 = 0; k0 < 256; k0 += 16) {
    float4 wv = *(const float4*)(A + (o0 + wr) * 256 + k0 + wc);
    float4 xv = *(const float4*)(B + (k0 + xr) * 4096 + n0 + xc);
    Wt[wr][wc + 0] = wv.x; Wt[wr][wc + 1] = wv.y;
    Wt[wr][wc + 2] = wv.z; Wt[wr][wc + 3] = wv.w;
    *(float4*)&Xt[xr][xc] = xv;
    __syncthreads();
#pragma unroll
    for (int kk = 0; kk < 16; ++kk) {
      float4 b = *(const float4*)&Xt[kk][tx << 2];
#pragma unroll
      for (int i = 0; i < 4; ++i) {
        float a = Wt[(ty << 2) + i][kk];
        acc[i].x += a * b.x; acc[i].y += a * b.y;
        acc[i].z += a * b.z; acc[i].w += a * b.w;
      }
    }
    __syncthreads();
  }

  if (SCATTER) {
#pragma unroll
    for (int i = 0; i < 4; ++i) {
      int o = o0 + (ty << 2) + i;
      int which = o >> 8, rem = o & 255;
      int h = rem >> 5, d = rem & 31;
      int n = n0 + (tx << 2);
      if (which == 1) {
        // KT[h][d][n..n+3]: contiguous float4
        *(float4*)(C1 + h * (HD * NTOK) + d * NTOK + n) = acc[i];
      } else {
        float* dst = (which == 0) ? C0 : C2;
        int base = h * (NTOK * HD) + d;
        dst[base + (n + 0) * HD] = acc[i].x;
        dst[base + (n + 1) * HD] = acc[i].y;
        dst[base + (n + 2) * HD] = acc[i].z;
        dst[base + (n + 3) * HD] = acc[i].w;
      }
    }
  } else {
#pragma unroll
    for (int i = 0; i < 4; ++i) {
      int o = o0 + (ty << 2) + i;
      *(float4*)(C0 + o * 4096 + n0 + (tx << 2)) = acc[i];
    }
  }
}

// ---- kernel 2a: l2norm Q rows [h][n][32], folds SCALE ---------------------

__global__ __launch_bounds__(256) void l2norm_q(float* __restrict__ Q) {
  const int tid = threadIdx.x;
  const int p = blockIdx.x * 8 + (tid >> 5);  // (head*4096+n) row index
  const int d = tid & 31;
  const int idx = p * HD + d;
  float v = Q[idx];
  float ss = v * v;
#pragma unroll
  for (int m = 16; m >= 1; m >>= 1) ss += __shfl_xor(ss, m, 32);
  float nrm = sqrtf(ss);
  Q[idx] = v * SCALE / fmaxf(nrm, 1e-12f);
}

// ---- kernel 2b: l2norm KT columns + fp16 d-pair pack (in place) -----------
// Reads KT[h][d][n] (fp32, all 32 d at fixed n), normalizes, writes packed
// fp16 pairs K16[h][d2][n] = (k[2d2],k[2d2+1]) over KT's first 16 rows.
// Aliasing is column-local (thread reads its column fully before storing).

__global__ __launch_bounds__(256) void l2norm_kt_pack(float* __restrict__ KT) {
  const int n = blockIdx.x * 256 + threadIdx.x;
  float* P = KT + blockIdx.y * (HD * NTOK) + n;
  float v[HD];
  float ss = 0.f;
#pragma unroll
  for (int d = 0; d < HD; ++d) {
    v[d] = P[d * NTOK];          // coalesced across lanes
    ss += v[d] * v[d];
  }
  float inv = 1.f / fmaxf(sqrtf(ss), 1e-12f);
  unsigned* O = (unsigned*)P;    // in-place: rows 0..15 as pair words
#pragma unroll
  for (int d2 = 0; d2 < 16; ++d2) {
#if USE_DOT2
    O[d2 * NTOK] = asu32(
        __builtin_amdgcn_cvt_pkrtz(v[2 * d2] * inv, v[2 * d2 + 1] * inv));
#else
    f16x2 p; p[0] = (__fp16)(v[2 * d2] * inv); p[1] = (__fp16)(v[2 * d2 + 1] * inv);
    O[d2 * NTOK] = asu32(p);
#endif
  }
}

// ---- kernel 3: fused attention (4 rows per block, column-partitioned) -----
// phase1: stage 4 q rows (fp32) + pack fp16 q d-pairs into LDS (once).
// phase2: thread tid owns cols {g*1024 + tid*4 + t}; 16 d2-iters of
//         {4 coalesced b128 K-pair loads + 4 broadcast b32 q-pair reads +
//          64 v_dot2_f32_f16} -> kr[4][16] fp32.
// phase3: hybrid selection (R19 window: RF while it<8 && width>65536, then
//         ulp bisection). Counts readfirstlane'd -> state SALU/SGPR;
//         per-row done-guards skip converged ballots.
// phase4: u8 weights packed 4 rows/col -> ONE ds_write_b128 per 4 cols;
//         exact integer denominators, block-reduced.  (R19 verbatim)
// phase5: PV scalar u8 (R19 verbatim, unroll 4).

__global__ __launch_bounds__(256, 4) void attn_kernel(
    const float* __restrict__ Q, const float* __restrict__ KT,
    const float* __restrict__ V, float* __restrict__ AO) {
  __shared__ __align__(16) unsigned char wtsT[NTOK][4];   // 16 KB, [m][row]
  __shared__ float qs[128];
  __shared__ unsigned qs2u[4][16];                        // fp16 q d-pairs
  __shared__ float pvred[4 * 8 * 4 * 4];                  // 2 KB
  __shared__ unsigned ired[2][4][2];                      // bisection dbuf
  __shared__ unsigned dred[4][4];                         // denom partials

  const int tid = threadIdx.x;
  const int wv = tid >> 6, lane = tid & 63;
  const int head = blockIdx.x & 7;          // head == blockIdx%8 -> XCD-pinned
  const int n0 = (blockIdx.x >> 3) << 2;

  const float* Qh = Q + head * (NTOK * HD);
  const float* KTh = KT + head * (HD * NTOK);
  const float* Vh = V + head * (NTOK * HD);

  // phase 1: stage the block's 4 q rows (already *SCALE from l2norm_q),
  // then pack fp16 d-pairs (once per block).
  if (tid < 128) qs[tid] = Qh[n0 * HD + tid];
  __syncthreads();
  if (tid < 64) {
    const int r = tid >> 4, d2 = tid & 15;
#if USE_DOT2
    qs2u[r][d2] = asu32(__builtin_amdgcn_cvt_pkrtz(
        qs[r * HD + (d2 << 1)], qs[r * HD + (d2 << 1) + 1]));
#else
    f16x2 p; p[0] = (__fp16)qs[r * HD + (d2 << 1)];
    p[1] = (__fp16)qs[r * HD + (d2 << 1) + 1];
    qs2u[r][d2] = asu32(p);
#endif
  }
  __syncthreads();

  // phase 2: kr[r][g*4+t] = score(row r, col g*1024 + tid*4 + t) via dot2
  // over d-pairs. Each K pair-word read by exactly ONE thread of the block.
  float kr[4][16];
#pragma unroll
  for (int r = 0; r < 4; ++r)
#pragma unroll
    for (int j = 0; j < 16; ++j) kr[r][j] = 0.f;

  const int cb = tid << 2;
  const unsigned* k16 = (const unsigned*)KTh + cb;   // [16][NTOK] pair words
#pragma unroll 1
  for (int d2 = 0; d2 < 16; ++d2) {
    const unsigned* kp = k16 + d2 * NTOK;
    const uint4 kv0 = *(const uint4*)(kp);
    const uint4 kv1 = *(const uint4*)(kp + 1024);
    const uint4 kv2 = *(const uint4*)(kp + 2048);
    const uint4 kv3 = *(const uint4*)(kp + 3072);
    const unsigned qu0 = qs2u[0][d2], qu1 = qs2u[1][d2];
    const unsigned qu2 = qs2u[2][d2], qu3 = qs2u[3][d2];
#if USE_DOT2
    const f16x2 q0 = asv2h(qu0), q1 = asv2h(qu1);
    const f16x2 q2 = asv2h(qu2), q3 = asv2h(qu3);
#define DOT16(r, qv)                                                         \
    kr[r][0]  = __builtin_amdgcn_fdot2(qv, asv2h(kv0.x), kr[r][0],  false);  \
    kr[r][1]  = __builtin_amdgcn_fdot2(qv, asv2h(kv0.y), kr[r][1],  false);  \
    kr[r][2]  = __builtin_amdgcn_fdot2(qv, asv2h(kv0.z), kr[r][2],  false);  \
    kr[r][3]  = __builtin_amdgcn_fdot2(qv, asv2h(kv0.w), kr[r][3],  false);  \
    kr[r][4]  = __builtin_amdgcn_fdot2(qv, asv2h(kv1.x), kr[r][4],  false);  \
    kr[r][5]  = __builtin_amdgcn_fdot2(qv, asv2h(kv1.y), kr[r][5],  false);  \
    kr[r][6]  = __builtin_amdgcn_fdot2(qv, asv2h(kv1.z), kr[r][6],  false);  \
    kr[r][7]  = __builtin_amdgcn_fdot2(qv, asv2h(kv1.w), kr[r][7],  false);  \
    kr[r][8]  = __builtin_amdgcn_fdot2(qv, asv2h(kv2.x), kr[r][8],  false);  \
    kr[r][9]  = __builtin_amdgcn_fdot2(qv, asv2h(kv2.y), kr[r][9],  false);  \
    kr[r][10] = __builtin_amdgcn_fdot2(qv, asv2h(kv2.z), kr[r][10], false);  \
    kr[r][11] = __builtin_amdgcn_fdot2(qv, asv2h(kv2.w), kr[r][11], false);  \
    kr[r][12] = __builtin_amdgcn_fdot2(qv, asv2h(kv3.x), kr[r][12], false);  \
    kr[r][13] = __builtin_amdgcn_fdot2(qv, asv2h(kv3.y), kr[r][13], false);  \
    kr[r][14] = __builtin_amdgcn_fdot2(qv, asv2h(kv3.z), kr[r][14], false);  \
    kr[r][15] = __builtin_amdgcn_fdot2(qv, asv2h(kv3.w), kr[r][15], false);
    DOT16(0, q0) DOT16(1, q1) DOT16(2, q2) DOT16(3, q3)
#undef DOT16
#else
    // fallback: decode pairs and FMA (compile insurance; fdot2 proven on HW)
#define DOTF(r, qu)                                                          \
    {                                                                        \
      const f16x2 qq = asv2h(qu);                                            \
      const float qa = (float)qq[0], qb = (float)qq[1];                      \
      const unsigned kk[16] = {kv0.x, kv0.y, kv0.z, kv0.w, kv1.x, kv1.y,     \
                               kv1.z, kv1.w, kv2.x, kv2.y, kv2.z, kv2.w,     \
                               kv3.x, kv3.y, kv3.z, kv3.w};                  \
      _Pragma("unroll")                                                      \
      for (int j = 0; j < 16; ++j) {                                         \
        const f16x2 kh = asv2h(kk[j]);                                       \
        kr[r][j] += qa * (float)kh[0] + qb * (float)kh[1];                   \
      }                                                                      \
    }
    DOTF(0, qu0) DOTF(1, qu1) DOTF(2, qu2) DOTF(3, qu3)
#undef DOTF
#endif
  }

  // phase 3: hybrid selection per row (R19 schedule). Bracket invariant
  // (key space): count(klo) >= KSEL, answer in [klo, khi]. RF probe while
  // it<8 && width>65536; ulp midpoint after. Exit on count==KSEL (kept set
  // == top-k of the COMPUTED scores; ties make the count skip KSEL so
  // ==KSEL is tie-free) or klo==khi (exact kth key).
  // |scores| <= 0.1768 < 0.25, so anchors (-0.25 -> 4096, +0.25 -> 0).
  // State block-uniform; counts readfirstlane'd -> SGPR/SALU resident.
  unsigned klo0 = 0x417FFFFFu, khi0 = 0xBE800000u;  // fkey(-.25), fkey(.25)
  unsigned klo1 = 0x417FFFFFu, khi1 = 0xBE800000u;
  unsigned klo2 = 0x417FFFFFu, khi2 = 0xBE800000u;
  unsigned klo3 = 0x417FFFFFu, khi3 = 0xBE800000u;
  float xlo0 = -0.25f, xhi0 = 0.25f, xlo1 = -0.25f, xhi1 = 0.25f;
  float xlo2 = -0.25f, xhi2 = 0.25f, xlo3 = -0.25f, xhi3 = 0.25f;
  int clo0 = NTOK, chi0 = 0, clo1 = NTOK, chi1 = 0;
  int clo2 = NTOK, chi2 = 0, clo3 = NTOK, chi3 = 0;
  bool dn0 = false, dn1 = false, dn2 = false, dn3 = false;
  int slot = 0;
#pragma unroll 1
  for (int it = 0; it < 40; ++it) {
    unsigned m0 = dn0 ? klo0
        : ((it < 8 && (khi0 - klo0) > 65536u)
               ? rfl_u(probe_rf(klo0, khi0, xlo0, xhi0, clo0, chi0))
               : klo0 + ((khi0 - klo0 + 1u) >> 1));
    unsigned m1 = dn1 ? klo1
        : ((it < 8 && (khi1 - klo1) > 65536u)
               ? rfl_u(probe_rf(klo1, khi1, xlo1, xhi1, clo1, chi1))
               : klo1 + ((khi1 - klo1 + 1u) >> 1));
    unsigned m2 = dn2 ? klo2
        : ((it < 8 && (khi2 - klo2) > 65536u)
               ? rfl_u(probe_rf(klo2, khi2, xlo2, xhi2, clo2, chi2))
               : klo2 + ((khi2 - klo2 + 1u) >> 1));
    unsigned m3 = dn3 ? klo3
        : ((it < 8 && (khi3 - klo3) > 65536u)
               ? rfl_u(probe_rf(klo3, khi3, xlo3, xhi3, clo3, chi3))
               : klo3 + ((khi3 - klo3 + 1u) >> 1));
    unsigned c0 = 0, c1 = 0, c2 = 0, c3 = 0;
    if (!dn0) {
      const float f0 = unfkey(m0);
#pragma unroll
      for (int j = 0; j < 16; ++j) c0 += __popcll(__ballot(kr[0][j] >= f0));
    }
    if (!dn1) {
      const float f1 = unfkey(m1);
#pragma unroll
      for (int j = 0; j < 16; ++j) c1 += __popcll(__ballot(kr[1][j] >= f1));
    }
    if (!dn2) {
      const float f2 = unfkey(m2);
#pragma unroll
      for (int j = 0; j < 16; ++j) c2 += __popcll(__ballot(kr[2][j] >= f2));
    }
    if (!dn3) {
      const float f3 = unfkey(m3);
#pragma unroll
      for (int j = 0; j < 16; ++j) c3 += __popcll(__ballot(kr[3][j] >= f3));
    }
    if (lane == 0) {
      ired[slot][wv][0] = c0 | (c1 << 16);
      ired[slot][wv][1] = c2 | (c3 << 16);
    }
    __syncthreads();
    unsigned a01 = rfl_u(ired[slot][0][0] + ired[slot][1][0] +
                         ired[slot][2][0] + ired[slot][3][0]);
    unsigned a23 = rfl_u(ired[slot][0][1] + ired[slot][1][1] +
                         ired[slot][2][1] + ired[slot][3][1]);
    slot ^= 1;
    int C0 = (int)(a01 & 0xFFFFu), C1 = (int)(a01 >> 16);
    int C2 = (int)(a23 & 0xFFFFu), C3 = (int)(a23 >> 16);
#define BUPD(C, klo, khi, xlo, xhi, clo, chi, dn, mk)                        \
    if (!dn) {                                                               \
      if (C == KSEL) { klo = mk; dn = true; }                                \
      else if (C > KSEL) { klo = mk; xlo = unfkey(mk); clo = C; }            \
      else { khi = mk - 1u; xhi = unfkey(mk); chi = C; }                     \
      if (klo >= khi) dn = true;                                             \
    }
    BUPD(C0, klo0, khi0, xlo0, xhi0, clo0, chi0, dn0, m0)
    BUPD(C1, klo1, khi1, xlo1, xhi1, clo1, chi1, dn1, m1)
    BUPD(C2, klo2, khi2, xlo2, xhi2, clo2, chi2, dn2, m2)
    BUPD(C3, klo3, khi3, xlo3, xhi3, clo3, chi3, dn3, m3)
#undef BUPD
    if (dn0 && dn1 && dn2 && dn3) break;   // uniform across block
  }
  const float tf0 = unfkey(klo0), tf1 = unfkey(klo1);
  const float tf2 = unfkey(klo2), tf3 = unfkey(klo3);

  // phase 4: u8 weights, 4 rows packed per column, b128 per 4 columns.
  // u = rint(exp(s) * 255/e^smax) in [179,255] kept, 0 masked. (R19)
  unsigned id0 = 0, id1 = 0, id2 = 0, id3 = 0;
#pragma unroll
  for (int g = 0; g < 4; ++g) {
    unsigned pk[4];
#pragma unroll
    for (int t = 0; t < 4; ++t) {
      const int j = (g << 2) + t;
      float s0 = kr[0][j], s1 = kr[1][j], s2 = kr[2][j], s3 = kr[3][j];
      unsigned u0 = (s0 >= tf0) ? (unsigned)rintf(exp2f(__builtin_fmaf(s0, 1.44269504f, LOG2C))) : 0u;
      unsigned u1 = (s1 >= tf1) ? (unsigned)rintf(exp2f(__builtin_fmaf(s1, 1.44269504f, LOG2C))) : 0u;
      unsigned u2 = (s2 >= tf2) ? (unsigned)rintf(exp2f(__builtin_fmaf(s2, 1.44269504f, LOG2C))) : 0u;
      unsigned u3 = (s3 >= tf3) ? (unsigned)rintf(exp2f(__builtin_fmaf(s3, 1.44269504f, LOG2C))) : 0u;
      id0 += u0; id1 += u1; id2 += u2; id3 += u3;
      pk[t] = u0 | (u1 << 8) | (u2 << 16) | (u3 << 24);
    }
    const int col = (g << 10) + cb;            // addr = col*4, 16B-aligned
    *(uint4*)&wtsT[col][0] = make_uint4(pk[0], pk[1], pk[2], pk[3]);
  }
  // exact integer denominators: wave-reduce then cross-wave sum
#pragma unroll
  for (int s = 1; s < 64; s <<= 1) {
    id0 += __shfl_xor(id0, s); id1 += __shfl_xor(id1, s);
    id2 += __shfl_xor(id2, s); id3 += __shfl_xor(id3, s);
  }
  if (lane == 0) *(uint4*)&dred[wv][0] = make_uint4(id0, id1, id2, id3);
  __syncthreads();  // wtsT + dred visible to all
  const float dnm0 = (float)(dred[0][0] + dred[1][0] + dred[2][0] + dred[3][0]);
  const float dnm1 = (float)(dred[0][1] + dred[1][1] + dred[2][1] + dred[3][1]);
  const float dnm2 = (float)(dred[0][2] + dred[1][2] + dred[2][2] + dred[3][2]);
  const float dnm3 = (float)(dred[0][3] + dred[1][3] + dred[2][3] + dred[3][3]);

  // phase 5: PV with integer weights (R19). wave wv covers m in
  // [wv*1024, +1024); unroll 4.
  const int slot5 = lane & 7, mg = lane >> 3;
  const int mbase = wv << 10;
  float av[4][4];
#pragma unroll
  for (int r = 0; r < 4; ++r)
#pragma unroll
    for (int c = 0; c < 4; ++c) av[r][c] = 0.f;

#pragma unroll 4
  for (int ii = 0; ii < 128; ++ii) {
    const int m = mbase + (ii << 3) + mg;
    unsigned wq = *(const unsigned*)&wtsT[m][0];   // one b32: rows 0..3
    float4 v = *(const float4*)(Vh + m * HD + (slot5 << 2));
    float w0 = (float)(wq & 0xFFu);          // v_cvt_f32_ubyte0
    float w1 = (float)((wq >> 8) & 0xFFu);   // v_cvt_f32_ubyte1
    float w2 = (float)((wq >> 16) & 0xFFu);  // v_cvt_f32_ubyte2
    float w3 = (float)(wq >> 24);            // v_cvt_f32_ubyte3
    av[0][0] += w0 * v.x; av[0][1] += w0 * v.y; av[0][2] += w0 * v.z; av[0][3] += w0 * v.w;
    av[1][0] += w1 * v.x; av[1][1] += w1 * v.y; av[1][2] += w1 * v.z; av[1][3] += w1 * v.w;
    av[2][0] += w2 * v.x; av[2][1] += w2 * v.y; av[2][2] += w2 * v.z; av[2][3] += w2 * v.w;
    av[3][0] += w3 * v.x; av[3][1] += w3 * v.y; av[3][2] += w3 * v.z; av[3][3] += w3 * v.w;
  }
  // reduce over mg (lane bits 3..5)
#pragma unroll
  for (int r = 0; r < 4; ++r)
#pragma unroll
    for (int c = 0; c < 4; ++c) {
      float x = av[r][c];
      x += __shfl_xor(x, 8); x += __shfl_xor(x, 16); x += __shfl_xor(x, 32);
      av[r][c] = x;
    }
  if (mg == 0) {
#pragma unroll
    for (int r = 0; r < 4; ++r)
#pragma unroll
      for (int c = 0; c < 4; ++c)
        pvred[(((wv << 3) + slot5) * 4 + r) * 4 + c] = av[r][c];
  }
  __syncthreads();

  if (tid < 128) {
    const int r = tid >> 5, d = tid & 31;
    const int sl = d >> 2, c = d & 3;
    float val = 0.f;
#pragma unroll
    for (int w = 0; w < 4; ++w) val += pvred[(((w << 3) + sl) * 4 + r) * 4 + c];
    float dn = (r == 0) ? dnm0 : (r == 1) ? dnm1 : (r == 2) ? dnm2 : dnm3;
    val /= dn;
    AO[(head * HD + d) * NTOK + n0 + r] = val;  // [C][N] for proj GEMM
  }
}

// ---- kernel 5: GroupNorm stats (32 groups of 8 ch x 4096 = 32768 vals) ----

__global__ __launch_bounds__(256) void gn_stats(const float* __restrict__ O,
                                                float* __restrict__ ST) {
  const int g = blockIdx.x, tid = threadIdx.x;
  const float4* p4 = (const float4*)(O + g * 32768);
  float s = 0.f, ss = 0.f;
  for (int i = tid; i < 8192; i += 256) {
    float4 v = p4[i];
    s += (v.x + v.y) + (v.z + v.w);
    ss += (v.x * v.x + v.y * v.y) + (v.z * v.z + v.w * v.w);
  }
#pragma unroll
  for (int m = 1; m < 64; m <<= 1) {
    s += __shfl_xor(s, m);
    ss += __shfl_xor(ss, m);
  }
  __shared__ float rs[4], rss[4];
  if ((tid & 63) == 0) { rs[tid >> 6] = s; rss[tid >> 6] = ss; }
  __syncthreads();
  if (tid == 0) {
    float S = rs[0] + rs[1] + rs[2] + rs[3];
    float SS = rss[0] + rss[1] + rss[2] + rss[3];
    float mean = S * (1.f / 32768.f);
    float var = SS * (1.f / 32768.f) - mean * mean;
    ST[g * 2] = mean;
    ST[g * 2 + 1] = rsqrtf(var + 1e-6f);
  }
}

// ---- kernel 6: GroupNorm apply (in place on d_out) ------------------------
// Indexes FLOAT4s: total 1048576/4 = 262144 -> grid 1024 x 256.

__global__ __launch_bounds__(256) void gn_apply(float* __restrict__ O,
                                                const float* __restrict__ ST,
                                                const float* __restrict__ gamma,
                                                const float* __restrict__ beta) {
  const int i4 = blockIdx.x * 256 + threadIdx.x;  // float4 index
  const int c = i4 >> 10, g = c >> 3;
  const float a = ST[g * 2 + 1] * gamma[c];
  const float b = beta[c] - ST[g * 2] * a;
  float4 v = *(float4*)(O + (i4 << 2));
  v.x = v.x * a + b; v.y = v.y * a + b; v.z = v.z * a + b; v.w = v.w * a + b;
  *(float4*)(O + (i4 << 2)) = v;
}

// ---- launch ---------------------------------------------------------------

extern "C" void kernel_launch(void* const* d_in, const int* in_sizes, int n_in,
                              void* d_out, int out_size, void* d_ws,
                              size_t ws_size, hipStream_t stream) {
  const float* x = (const float*)d_in[0];       // [256][4096]
  const float* w_qkv = (const float*)d_in[1];   // [768][256]
  const float* w_proj = (const float*)d_in[2];  // [256][256]
  const float* gamma = (const float*)d_in[3];   // [256]
  const float* beta = (const float*)d_in[4];    // [256]
  float* out = (float*)d_out;                   // [256][4096]

  float* Q = (float*)d_ws;          // [8][4096][32]
  float* KT = Q + 1048576;          // [8][32][4096] fp32 -> fp16 pairs in place
  float* V = KT + 1048576;          // [8][4096][32]
  float* AO = V + 1048576;          // [256][4096]
  float* ST = AO + 1048576;         // [32][2]

  gemm_k256<true><<<dim3(64, 12), 256, 0, stream>>>(w_qkv, x, Q, KT, V);
  l2norm_q<<<4096, 256, 0, stream>>>(Q);
  l2norm_kt_pack<<<dim3(16, 8), 256, 0, stream>>>(KT);
  attn_kernel<<<8192, 256, 0, stream>>>(Q, KT, V, AO);
  gemm_k256<false><<<dim3(64, 4), 256, 0, stream>>>(w_proj, AO, out, nullptr, nullptr);
  gn_stats<<<32, 256, 0, stream>>>(out, ST);
  gn_apply<<<1024, 256, 0, stream>>>(out, ST, gamma, beta);
}